// Round 2
// baseline (2104.290 us; speedup 1.0000x reference)
//
#include <hip/hip_runtime.h>
#include <hip/hip_bf16.h>
#include <math.h>

typedef unsigned short u16;
typedef unsigned int   u32;

// Problem constants
constexpr int G  = 8;      // groups (conv spatial length)
constexpr int D  = 128;    // d_chunk
constexpr int H  = 256;    // hidden channels
constexpr int K  = 3;      // kernel size
constexpr int DM = 1024;   // d_model
constexpr int PK = 1024;   // packed = G*D
constexpr int NTOK = 8 * 2048;   // B*S
constexpr int TPB  = 4;          // tokens per block

__device__ __forceinline__ float bf2f(u16 u) {
    union { u32 i; float f; } v; v.i = ((u32)u) << 16; return v.f;
}
__device__ __forceinline__ u16 f2bf(float f) {
    union { float f; u32 i; } v; v.f = f;
    u32 x = v.i;
    return (u16)((x + 0x7fffu + ((x >> 16) & 1u)) >> 16);  // RNE
}
__device__ __forceinline__ float f4c(const float4 v, int j) {
    return j == 0 ? v.x : j == 1 ? v.y : j == 2 ? v.z : v.w;
}

// dtype-generic loads/stores: ISBF=true -> bf16 (u16), false -> fp32
template <bool ISBF>
__device__ __forceinline__ float ld1(const void* p, size_t i) {
    if (ISBF) return bf2f(((const u16*)p)[i]);
    else      return ((const float*)p)[i];
}
template <bool ISBF>
__device__ __forceinline__ float4 ld4(const void* p, size_t i) {  // i % 4 == 0
    if (ISBF) {
        ushort4 v = *(const ushort4*)((const u16*)p + i);
        return make_float4(bf2f(v.x), bf2f(v.y), bf2f(v.z), bf2f(v.w));
    } else {
        return *(const float4*)((const float*)p + i);
    }
}
template <bool ISBF>
__device__ __forceinline__ void st4(void* p, size_t i, float4 v) {
    if (ISBF) {
        ushort4 o; o.x = f2bf(v.x); o.y = f2bf(v.y); o.z = f2bf(v.z); o.w = f2bf(v.w);
        *(ushort4*)((u16*)p + i) = o;
    } else {
        *(float4*)((float*)p + i) = v;
    }
}

// Decide on-device whether tensors are bf16 or fp32 by decoding the first
// 2048 u16 of x as bf16 and counting sane exponents. bf16 N(0,1) data ->
// ~100% pass; fp32 data -> low-u16 halves are mantissa bits (uniform
// exponents, ~12.5% pass) -> total ~56%. Threshold 1900/2048.
__global__ void detect_dtype(const void* xraw, int* flag) {
    __shared__ int cnt[256];
    const u32* xw = (const u32*)xraw;
    int tid = threadIdx.x, c = 0;
#pragma unroll
    for (int k = 0; k < 4; ++k) {
        u32 w = xw[tid * 4 + k];
#pragma unroll
        for (int h = 0; h < 2; ++h) {
            u16 u = (u16)(w >> (16 * h));
            int e = (u >> 7) & 0xFF;
            if ((u & 0x7FFF) == 0 || (e >= 112 && e <= 143)) ++c;
        }
    }
    cnt[tid] = c;
    __syncthreads();
    for (int s = 128; s > 0; s >>= 1) {
        if (tid < s) cnt[tid] += cnt[tid + s];
        __syncthreads();
    }
    if (tid == 0) flag[0] = (cnt[0] >= 1900) ? 1 : 0;
}

// Transpose conv weights into fp32, lane-coalesced layouts:
//   w1t[(k*D + d)*H + h] = w1[h, d, k]
//   w2t[(k*H + h)*D + d] = w2[d, h, k]
template <bool ISBF>
__global__ void prep_weights(const void* __restrict__ w1, const void* __restrict__ w2,
                             float* __restrict__ w1t, float* __restrict__ w2t,
                             const int* __restrict__ flag) {
    if ((flag[0] != 0) != ISBF) return;
    int idx = blockIdx.x * 256 + threadIdx.x;
    if (idx < H * D * K) {
        int h = idx / (D * K); int r = idx % (D * K); int d = r / K; int k = r % K;
        w1t[(k * D + d) * H + h] = ld1<ISBF>(w1, idx);
    }
    if (idx < D * H * K) {
        int d = idx / (H * K); int r = idx % (H * K); int h = r / K; int k = r % K;
        w2t[(k * H + h) * D + d] = ld1<ISBF>(w2, idx);
    }
}

template <bool ISBF, bool USE_WS>
__global__ __launch_bounds__(256)
void slotconv_main(const void* __restrict__ x,
                   const void* __restrict__ slot_gate,
                   const void* __restrict__ slot_bias,
                   const void* __restrict__ pre_g,
                   const void* __restrict__ pre_b,
                   const void* __restrict__ w1raw,
                   const void* __restrict__ b1,
                   const void* __restrict__ w2raw,
                   const void* __restrict__ b2,
                   const void* __restrict__ pack_g,
                   const void* __restrict__ pack_b,
                   const void* __restrict__ Wm,
                   const void* __restrict__ bm,
                   const float* __restrict__ w1t,
                   const float* __restrict__ w2t,
                   void* __restrict__ out,
                   const int* __restrict__ flag) {
    if ((flag[0] != 0) != ISBF) return;

    __shared__ float resid[G * D];             // 4 KB
    __shared__ float xnpad[(G + 2) * D];       // 5 KB, rows 0 and 9 zero
    __shared__ float midpad[(G + 2) * H];      // 10 KB, rows 0 and 9 zero
    __shared__ float zbuf[TPB][PK];            // 16 KB
    __shared__ float red[8];

    const int tid = threadIdx.x;

    if (tid < D) { xnpad[tid] = 0.f; xnpad[(G + 1) * D + tid] = 0.f; }
    midpad[tid] = 0.f; midpad[(G + 1) * H + tid] = 0.f;

    const int e0 = 4 * tid;          // 4 consecutive packed elements
    const int d0 = e0 & (D - 1);
    const int g0 = tid >> 5;         // group for LN1

    // hoisted per-block parameters (reused over TPB tokens)
    float gate[4], bias[4], pgf[4], pbf[4];
    {
        float4 sg4 = ld4<ISBF>(slot_gate, e0);
        float4 sb4 = ld4<ISBF>(slot_bias, e0);
        float4 pg4 = ld4<ISBF>(pre_g, d0);
        float4 pb4 = ld4<ISBF>(pre_b, d0);
#pragma unroll
        for (int j = 0; j < 4; ++j) {
            gate[j] = 2.f / (1.f + __expf(-f4c(sg4, j)));
            bias[j] = f4c(sb4, j);
            pgf[j] = f4c(pg4, j);
            pbf[j] = f4c(pb4, j);
        }
    }

    for (int t = 0; t < TPB; ++t) {
        __syncthreads();   // protect LDS reuse across tokens
        const int tok = blockIdx.x * TPB + t;

        // ---- stage 1: load x, gate+bias, residual, LN1 over D per group ----
        {
            float4 x4 = ld4<ISBF>(x, (size_t)tok * PK + e0);
            float v[4];
#pragma unroll
            for (int j = 0; j < 4; ++j) v[j] = f4c(x4, j) * gate[j] + bias[j];
            *(float4*)&resid[e0] = make_float4(v[0], v[1], v[2], v[3]);

            float s = v[0] + v[1] + v[2] + v[3];
            float ss = v[0]*v[0] + v[1]*v[1] + v[2]*v[2] + v[3]*v[3];
#pragma unroll
            for (int m = 1; m < 32; m <<= 1) {   // 32 lanes cover one group
                s  += __shfl_xor(s,  m);
                ss += __shfl_xor(ss, m);
            }
            float mean = s * (1.f / 128.f);
            float var  = ss * (1.f / 128.f) - mean * mean;
            float rstd = rsqrtf(var + 1e-5f);
            float xn[4];
#pragma unroll
            for (int j = 0; j < 4; ++j) xn[j] = (v[j] - mean) * rstd * pgf[j] + pbf[j];
            *(float4*)&xnpad[(g0 + 1) * D + d0] = make_float4(xn[0], xn[1], xn[2], xn[3]);
        }
        __syncthreads();

        // ---- stage 2: conv1 (D->H over g, pad 1) + GELU(exact) ----
        {
            const int h = tid;
            float acc[G];
#pragma unroll
            for (int g = 0; g < G; ++g) acc[g] = 0.f;

            for (int d4 = 0; d4 < D; d4 += 4) {
                float4 xr4[G + 2];
#pragma unroll
                for (int r = 0; r < G + 2; ++r)
                    xr4[r] = *(const float4*)&xnpad[r * D + d4];   // wave-uniform broadcast
#pragma unroll
                for (int j = 0; j < 4; ++j) {
                    const int d = d4 + j;
                    float wk0, wk1, wk2;
                    if (USE_WS) {
                        wk0 = w1t[(0 * D + d) * H + h];
                        wk1 = w1t[(1 * D + d) * H + h];
                        wk2 = w1t[(2 * D + d) * H + h];
                    } else {
                        size_t o = (size_t)h * (D * K) + d * K;
                        wk0 = ld1<ISBF>(w1raw, o);
                        wk1 = ld1<ISBF>(w1raw, o + 1);
                        wk2 = ld1<ISBF>(w1raw, o + 2);
                    }
#pragma unroll
                    for (int g = 0; g < G; ++g) {
                        acc[g] += f4c(xr4[g + 0], j) * wk0;
                        acc[g] += f4c(xr4[g + 1], j) * wk1;
                        acc[g] += f4c(xr4[g + 2], j) * wk2;
                    }
                }
            }
            float b1h = ld1<ISBF>(b1, tid);
#pragma unroll
            for (int g = 0; g < G; ++g) {
                float m = acc[g] + b1h;
                float gel = 0.5f * m * (1.f + erff(m * 0.70710678118654752f));
                midpad[(g + 1) * H + h] = gel;
            }
        }
        __syncthreads();

        // ---- stage 3: conv2 (H->D over g, pad 1) + residual + LN2 + pack affine ----
        {
            const int dd = tid & (D - 1);
            const int gh = tid >> 7;     // which half of the 8 g-positions
            float acc2[4] = {0.f, 0.f, 0.f, 0.f};

            for (int h4 = 0; h4 < H; h4 += 4) {
                float4 mr4[6];
#pragma unroll
                for (int r = 0; r < 6; ++r)
                    mr4[r] = *(const float4*)&midpad[(gh * 4 + r) * H + h4];  // broadcast
#pragma unroll
                for (int j = 0; j < 4; ++j) {
                    const int h = h4 + j;
                    float wk0, wk1, wk2;
                    if (USE_WS) {
                        wk0 = w2t[(0 * H + h) * D + dd];
                        wk1 = w2t[(1 * H + h) * D + dd];
                        wk2 = w2t[(2 * H + h) * D + dd];
                    } else {
                        size_t o = (size_t)dd * (H * K) + h * K;
                        wk0 = ld1<ISBF>(w2raw, o);
                        wk1 = ld1<ISBF>(w2raw, o + 1);
                        wk2 = ld1<ISBF>(w2raw, o + 2);
                    }
#pragma unroll
                    for (int jj = 0; jj < 4; ++jj) {
                        acc2[jj] += f4c(mr4[jj + 0], j) * wk0;
                        acc2[jj] += f4c(mr4[jj + 1], j) * wk1;
                        acc2[jj] += f4c(mr4[jj + 2], j) * wk2;
                    }
                }
            }

            float b2d = ld1<ISBF>(b2, dd);
            float vz[4], s = 0.f, ss = 0.f;
#pragma unroll
            for (int j = 0; j < 4; ++j) {
                int e = (gh * 4 + j) * D + dd;
                float val = acc2[j] + b2d + resid[e];
                vz[j] = val; s += val; ss += val * val;
            }
#pragma unroll
            for (int m = 1; m < 64; m <<= 1) {
                s  += __shfl_xor(s,  m);
                ss += __shfl_xor(ss, m);
            }
            const int wid = tid >> 6;
            if ((tid & 63) == 0) { red[wid * 2] = s; red[wid * 2 + 1] = ss; }
            __syncthreads();
            float st  = red[0] + red[2] + red[4] + red[6];
            float sst = red[1] + red[3] + red[5] + red[7];
            float mean = st * (1.f / 1024.f);
            float var  = sst * (1.f / 1024.f) - mean * mean;
            float rstd = rsqrtf(var + 1e-5f);
#pragma unroll
            for (int j = 0; j < 4; ++j) {
                int e = (gh * 4 + j) * D + dd;
                float pg = ld1<ISBF>(pack_g, e);
                float pb = ld1<ISBF>(pack_b, e);
                zbuf[t][e] = (vz[j] - mean) * rstd * pg + pb;
            }
        }
    }
    __syncthreads();

    // ---- stage 4: out[tok, m] = z[tok, :] @ Wm[:, m] + bm[m] for TPB tokens ----
    {
        float accm[TPB][4];
#pragma unroll
        for (int t = 0; t < TPB; ++t)
#pragma unroll
            for (int j = 0; j < 4; ++j) accm[t][j] = 0.f;

        for (int p4 = 0; p4 < PK; p4 += 4) {
            float4 z4[TPB];
#pragma unroll
            for (int t = 0; t < TPB; ++t) z4[t] = *(const float4*)&zbuf[t][p4];  // broadcast
#pragma unroll
            for (int pp = 0; pp < 4; ++pp) {
                const int p = p4 + pp;
                float4 w4 = ld4<ISBF>(Wm, (size_t)p * DM + e0);
#pragma unroll
                for (int t = 0; t < TPB; ++t) {
                    float zp = f4c(z4[t], pp);
                    accm[t][0] += zp * w4.x;
                    accm[t][1] += zp * w4.y;
                    accm[t][2] += zp * w4.z;
                    accm[t][3] += zp * w4.w;
                }
            }
        }

        float4 bm4 = ld4<ISBF>(bm, e0);
#pragma unroll
        for (int t = 0; t < TPB; ++t) {
            const int tok = blockIdx.x * TPB + t;
            float4 o = make_float4(accm[t][0] + bm4.x, accm[t][1] + bm4.y,
                                   accm[t][2] + bm4.z, accm[t][3] + bm4.w);
            st4<ISBF>(out, (size_t)tok * DM + e0, o);
        }
    }
}

extern "C" void kernel_launch(void* const* d_in, const int* in_sizes, int n_in,
                              void* d_out, int out_size, void* d_ws, size_t ws_size,
                              hipStream_t stream) {
    const void* x   = d_in[0];
    const void* sg  = d_in[1];
    const void* sb  = d_in[2];
    const void* pg  = d_in[3];
    const void* pb  = d_in[4];
    const void* w1  = d_in[5];
    const void* b1  = d_in[6];
    const void* w2  = d_in[7];
    const void* b2  = d_in[8];
    const void* pkg = d_in[9];
    const void* pkb = d_in[10];
    const void* Wm  = d_in[11];
    const void* bm  = d_in[12];

    int* flag  = (int*)d_ws;
    float* w1t = (float*)((char*)d_ws + 16);
    float* w2t = w1t + H * D * K;
    const size_t ws_needed = 16 + (size_t)2 * H * D * K * sizeof(float);

    detect_dtype<<<1, 256, 0, stream>>>(x, flag);

    if (ws_size >= ws_needed) {
        prep_weights<true ><<<(H * D * K + 255) / 256, 256, 0, stream>>>(w1, w2, w1t, w2t, flag);
        prep_weights<false><<<(H * D * K + 255) / 256, 256, 0, stream>>>(w1, w2, w1t, w2t, flag);
        slotconv_main<true , true ><<<NTOK / TPB, 256, 0, stream>>>(
            x, sg, sb, pg, pb, w1, b1, w2, b2, pkg, pkb, Wm, bm, w1t, w2t, d_out, flag);
        slotconv_main<false, true ><<<NTOK / TPB, 256, 0, stream>>>(
            x, sg, sb, pg, pb, w1, b1, w2, b2, pkg, pkb, Wm, bm, w1t, w2t, d_out, flag);
    } else {
        slotconv_main<true , false><<<NTOK / TPB, 256, 0, stream>>>(
            x, sg, sb, pg, pb, w1, b1, w2, b2, pkg, pkb, Wm, bm, nullptr, nullptr, d_out, flag);
        slotconv_main<false, false><<<NTOK / TPB, 256, 0, stream>>>(
            x, sg, sb, pg, pb, w1, b1, w2, b2, pkg, pkb, Wm, bm, nullptr, nullptr, d_out, flag);
    }
}

// Round 4
// 334.813 us; speedup vs baseline: 6.2850x; 6.2850x over previous
//
#include <hip/hip_runtime.h>
#include <hip/hip_bf16.h>
#include <math.h>

typedef unsigned short u16;
typedef unsigned int   u32;
typedef __attribute__((ext_vector_type(8))) short short8;   // 8 bf16
typedef __attribute__((ext_vector_type(4))) float f32x4;    // MFMA acc

// Problem constants
constexpr int G  = 8;
constexpr int D  = 128;
constexpr int H  = 256;
constexpr int DM = 1024;
constexpr int PK = 1024;
constexpr int NTOK = 8 * 2048;   // 16384

// ---------- scalar helpers ----------
__device__ __forceinline__ float bf2f(u16 u) {
    union { u32 i; float f; } v; v.i = ((u32)u) << 16; return v.f;
}
__device__ __forceinline__ u16 f2bf(float f) {
    union { float f; u32 i; } v; v.f = f;
    u32 x = v.i;
    return (u16)((x + 0x7fffu + ((x >> 16) & 1u)) >> 16);  // RNE
}
__device__ __forceinline__ float f4c(const float4 v, int j) {
    return j == 0 ? v.x : j == 1 ? v.y : j == 2 ? v.z : v.w;
}
template <bool ISBF>
__device__ __forceinline__ float ld1(const void* p, size_t i) {
    if (ISBF) return bf2f(((const u16*)p)[i]);
    else      return ((const float*)p)[i];
}
template <bool ISBF>
__device__ __forceinline__ float4 ld4(const void* p, size_t i) {  // i % 4 == 0
    if (ISBF) {
        ushort4 v = *(const ushort4*)((const u16*)p + i);
        return make_float4(bf2f(v.x), bf2f(v.y), bf2f(v.z), bf2f(v.w));
    } else {
        return *(const float4*)((const float*)p + i);
    }
}
template <bool ISBF>
__device__ __forceinline__ void st4(void* p, size_t i, float4 v) {
    if (ISBF) {
        ushort4 o; o.x = f2bf(v.x); o.y = f2bf(v.y); o.z = f2bf(v.z); o.w = f2bf(v.w);
        *(ushort4*)((u16*)p + i) = o;
    } else {
        *(float4*)((float*)p + i) = v;
    }
}
// tanh-form GELU (max dev vs exact erf-GELU ~3e-4, tolerance 6.4e-2)
__device__ __forceinline__ float gelu_f(float v) {
    float u = v * (0.7978845608028654f + 0.0356774081f * v * v);
    float e = __expf(2.f * u);
    float th = 1.f - 2.f / (e + 1.f);
    return 0.5f * v * (1.f + th);
}

// ---------- dtype detect (proven R2) ----------
__global__ void detect_dtype(const void* xraw, int* flag) {
    __shared__ int cnt[256];
    const u32* xw = (const u32*)xraw;
    int tid = threadIdx.x, c = 0;
#pragma unroll
    for (int k = 0; k < 4; ++k) {
        u32 w = xw[tid * 4 + k];
#pragma unroll
        for (int h = 0; h < 2; ++h) {
            u16 u = (u16)(w >> (16 * h));
            int e = (u >> 7) & 0xFF;
            if ((u & 0x7FFF) == 0 || (e >= 112 && e <= 143)) ++c;
        }
    }
    cnt[tid] = c;
    __syncthreads();
    for (int s = 128; s > 0; s >>= 1) {
        if (tid < s) cnt[tid] += cnt[tid + s];
        __syncthreads();
    }
    if (tid == 0) flag[0] = (cnt[0] >= 1900) ? 1 : 0;
}

// ---------- MFMA-path weight prep ----------
// w1b[tap][h][d] ; w2b[tap][d][h] ; wmt[n][k] (WmT)  — all bf16
template <bool ISBF>
__global__ void prep_mfma(const void* __restrict__ w1, const void* __restrict__ w2,
                          const void* __restrict__ Wm,
                          u16* __restrict__ w1b, u16* __restrict__ w2b,
                          u16* __restrict__ wmt, const int* __restrict__ flag) {
    if ((flag[0] != 0) != ISBF) return;
    int idx = blockIdx.x * 256 + threadIdx.x;
    if (idx < 3 * H * D) {
        int k = idx / (H * D); int r = idx % (H * D); int h = r / D; int d = r % D;
        w1b[idx] = f2bf(ld1<ISBF>(w1, (size_t)(h * D + d) * 3 + k));
    }
    if (idx < 3 * D * H) {
        int k = idx / (D * H); int r = idx % (D * H); int d = r / H; int h = r % H;
        w2b[idx] = f2bf(ld1<ISBF>(w2, (size_t)(d * H + h) * 3 + k));
    }
    if (idx < DM * DM) {
        int kk = idx / DM, n = idx % DM;               // coalesced read of Wm
        wmt[(size_t)n * DM + kk] = f2bf(ld1<ISBF>(Wm, (size_t)kk * DM + n));
    }
}

// ---------- fused gate+LN1+conv1+GELU+conv2+LN2 -> z (bf16) ----------
// 8 tokens/block, 256 threads (4 waves), 16x16x32 bf16 MFMA.
constexpr int XS = 136;   // xnpad row stride (128 + 8 pad)
constexpr int MS = 264;   // midpad row stride (256 + 8 pad)

template <bool ISBF>
__global__ __launch_bounds__(256, 2)
void conv_fused(const void* __restrict__ x,
                const void* __restrict__ slot_gate,
                const void* __restrict__ slot_bias,
                const void* __restrict__ pre_g,
                const void* __restrict__ pre_b,
                const void* __restrict__ b1,
                const void* __restrict__ b2,
                const void* __restrict__ pack_g,
                const void* __restrict__ pack_b,
                const u16* __restrict__ w1b,
                const u16* __restrict__ w2b,
                u16* __restrict__ zout,
                const int* __restrict__ flag) {
    if ((flag[0] != 0) != ISBF) return;

    __shared__ u16 xnpad[8 * 10 * XS];     // 21760 B
    __shared__ u16 midpad[8 * 10 * MS];    // 42240 B
    __shared__ u16 gateb[PK], biasb[PK], packgb[PK], packbb[PK];  // 8 KB
    __shared__ float red_s[8][4], red_ss[8][4];

    const int tid  = threadIdx.x;
    const int lane = tid & 63, w = tid >> 6;
    const int quad = lane >> 4, col = lane & 15;
    const size_t tok0 = (size_t)blockIdx.x * 8;

    // ---- stage 0: stage params to LDS, zero pad rows ----
    {
        int e0 = 4 * tid;
        float4 sg4 = ld4<ISBF>(slot_gate, e0);
        float4 sb4 = ld4<ISBF>(slot_bias, e0);
        float4 pg4 = ld4<ISBF>(pack_g, e0);
        float4 pb4 = ld4<ISBF>(pack_b, e0);
#pragma unroll
        for (int j = 0; j < 4; ++j) {
            gateb[e0 + j]  = f2bf(2.f / (1.f + __expf(-f4c(sg4, j))));
            biasb[e0 + j]  = f2bf(f4c(sb4, j));
            packgb[e0 + j] = f2bf(f4c(pg4, j));
            packbb[e0 + j] = f2bf(f4c(pb4, j));
        }
        // xnpad pad rows (16 rows x 128 cols)
        {
            int li = tid * 8; int r = li >> 7, c = li & 127;
            int t = r >> 1, wh = r & 1;
            u16* p = &xnpad[(t * 10 + wh * 9) * XS + c];
            *(ushort4*)p = make_ushort4(0, 0, 0, 0);
            *(ushort4*)(p + 4) = make_ushort4(0, 0, 0, 0);
        }
        // midpad pad rows (16 rows x 256 cols)
        {
            int li = tid * 16; int r = li >> 8, c = li & 255;
            int t = r >> 1, wh = r & 1;
            u16* p = &midpad[(t * 10 + wh * 9) * MS + c];
#pragma unroll
            for (int q = 0; q < 4; ++q) *(ushort4*)(p + 4 * q) = make_ushort4(0, 0, 0, 0);
        }
    }

    // per-thread slice for stage 1
    const int e0 = 4 * tid;
    const int d0 = e0 & (D - 1);
    const int g0 = tid >> 5;
    float gf[4], bff[4], pgf[4], pbf[4];
    {
        float4 sg4 = ld4<ISBF>(slot_gate, e0);
        float4 sb4 = ld4<ISBF>(slot_bias, e0);
        float4 pg4 = ld4<ISBF>(pre_g, d0);
        float4 pb4 = ld4<ISBF>(pre_b, d0);
#pragma unroll
        for (int j = 0; j < 4; ++j) {
            gf[j]  = 2.f / (1.f + __expf(-f4c(sg4, j)));
            bff[j] = f4c(sb4, j);
            pgf[j] = f4c(pg4, j);
            pbf[j] = f4c(pb4, j);
        }
    }
    __syncthreads();

    // ---- stage 1: gate+bias, LN1, write xn (bf16) ----
    for (int t = 0; t < 8; ++t) {
        float4 x4 = ld4<ISBF>(x, (tok0 + t) * PK + e0);
        float v[4];
#pragma unroll
        for (int j = 0; j < 4; ++j) v[j] = f4c(x4, j) * gf[j] + bff[j];
        float s = v[0] + v[1] + v[2] + v[3];
        float ss = v[0]*v[0] + v[1]*v[1] + v[2]*v[2] + v[3]*v[3];
#pragma unroll
        for (int m = 1; m < 32; m <<= 1) {
            s  += __shfl_xor(s,  m);
            ss += __shfl_xor(ss, m);
        }
        float mean = s * (1.f / 128.f);
        float var  = ss * (1.f / 128.f) - mean * mean;
        float rstd = rsqrtf(var + 1e-5f);
        ushort4 o;
        o.x = f2bf((v[0] - mean) * rstd * pgf[0] + pbf[0]);
        o.y = f2bf((v[1] - mean) * rstd * pgf[1] + pbf[1]);
        o.z = f2bf((v[2] - mean) * rstd * pgf[2] + pbf[2]);
        o.w = f2bf((v[3] - mean) * rstd * pgf[3] + pbf[3]);
        *(ushort4*)&xnpad[(t * 10 + g0 + 1) * XS + d0] = o;
    }
    __syncthreads();

    // per-lane (t,g) row bases for the 4 N-tiles (shared by conv1/conv2)
    int rowb[4];
#pragma unroll
    for (int nt = 0; nt < 4; ++nt) {
        int n = nt * 16 + col;
        rowb[nt] = (n >> 3) * 10 + (n & 7);
    }
    const int kq = quad * 8;

    // ---- stage 2: conv1 via MFMA (C[h][(t,g)]), + bias + GELU -> midpad ----
    {
        f32x4 acc1[4][4] = {};   // [mtl][nt]
        for (int ktap = 0; ktap < 3; ++ktap) {
#pragma unroll
            for (int kk = 0; kk < 4; ++kk) {
                short8 bfr[4];
#pragma unroll
                for (int nt = 0; nt < 4; ++nt)
                    bfr[nt] = *(const short8*)&xnpad[(rowb[nt] + ktap) * XS + kk * 32 + kq];
#pragma unroll
                for (int mtl = 0; mtl < 4; ++mtl) {
                    int h = w * 64 + mtl * 16 + col;
                    short8 afr = *(const short8*)(w1b + (size_t)(ktap * H + h) * D + kk * 32 + kq);
#pragma unroll
                    for (int nt = 0; nt < 4; ++nt)
                        acc1[mtl][nt] = __builtin_amdgcn_mfma_f32_16x16x32_bf16(
                            afr, bfr[nt], acc1[mtl][nt], 0, 0, 0);
                }
            }
        }
        // epilogue: rows = h (quad*4+r), cols = (t,g)
#pragma unroll
        for (int mtl = 0; mtl < 4; ++mtl) {
            int hq = w * 64 + mtl * 16 + quad * 4;
            float4 b1q = ld4<ISBF>(b1, hq);
#pragma unroll
            for (int nt = 0; nt < 4; ++nt) {
                int n = nt * 16 + col; int t = n >> 3, g = n & 7;
                ushort4 o;
                o.x = f2bf(gelu_f(acc1[mtl][nt][0] + b1q.x));
                o.y = f2bf(gelu_f(acc1[mtl][nt][1] + b1q.y));
                o.z = f2bf(gelu_f(acc1[mtl][nt][2] + b1q.z));
                o.w = f2bf(gelu_f(acc1[mtl][nt][3] + b1q.w));
                *(ushort4*)&midpad[(t * 10 + g + 1) * MS + hq] = o;
            }
        }
    }
    __syncthreads();

    // ---- stage 3: conv2 via MFMA (C[d][(t,g)]) + bias + residual + LN2 + pack -> z ----
    {
        f32x4 acc2[2][4] = {};   // [mtl][nt]
        for (int ktap = 0; ktap < 3; ++ktap) {
#pragma unroll
            for (int kk = 0; kk < 8; ++kk) {
                short8 bfr[4];
#pragma unroll
                for (int nt = 0; nt < 4; ++nt)
                    bfr[nt] = *(const short8*)&midpad[(rowb[nt] + ktap) * MS + kk * 32 + kq];
#pragma unroll
                for (int mtl = 0; mtl < 2; ++mtl) {
                    int d = w * 32 + mtl * 16 + col;
                    short8 afr = *(const short8*)(w2b + (size_t)(ktap * D + d) * H + kk * 32 + kq);
#pragma unroll
                    for (int nt = 0; nt < 4; ++nt)
                        acc2[mtl][nt] = __builtin_amdgcn_mfma_f32_16x16x32_bf16(
                            afr, bfr[nt], acc2[mtl][nt], 0, 0, 0);
                }
            }
        }
        // epilogue: val = conv2 + b2 + resid(x*gate+bias); LN2 over 1024/token
        float vals[2][4][4];
        float s[4] = {0.f, 0.f, 0.f, 0.f}, ss[4] = {0.f, 0.f, 0.f, 0.f};
#pragma unroll
        for (int mtl = 0; mtl < 2; ++mtl) {
            int dq = w * 32 + mtl * 16 + quad * 4;
            float4 b2q = ld4<ISBF>(b2, dq);
#pragma unroll
            for (int nt = 0; nt < 4; ++nt) {
                int n = nt * 16 + col; int t = n >> 3, g = n & 7;
                float4 xr = ld4<ISBF>(x, (tok0 + t) * PK + g * D + dq);
#pragma unroll
                for (int r = 0; r < 4; ++r) {
                    int e = g * D + dq + r;
                    float resid = f4c(xr, r) * bf2f(gateb[e]) + bf2f(biasb[e]);
                    float val = acc2[mtl][nt][r] + f4c(b2q, r) + resid;
                    vals[mtl][nt][r] = val;
                    s[nt] += val; ss[nt] += val * val;
                }
            }
        }
        // reduce over lanes sharing token t: col bits 0-2 (g) and quad bits 4-5 (d)
        // masks {1,2,4,16,32}  (BUGFIX R3: was 8<<m -> {64,128} = self-reads)
#pragma unroll
        for (int nt = 0; nt < 4; ++nt) {
            s[nt] += __shfl_xor(s[nt], 1);  ss[nt] += __shfl_xor(ss[nt], 1);
            s[nt] += __shfl_xor(s[nt], 2);  ss[nt] += __shfl_xor(ss[nt], 2);
            s[nt] += __shfl_xor(s[nt], 4);  ss[nt] += __shfl_xor(ss[nt], 4);
            s[nt] += __shfl_xor(s[nt], 16); ss[nt] += __shfl_xor(ss[nt], 16);
            s[nt] += __shfl_xor(s[nt], 32); ss[nt] += __shfl_xor(ss[nt], 32);
        }
        if (quad == 0 && (col & 7) == 0) {
#pragma unroll
            for (int nt = 0; nt < 4; ++nt) {
                int t = 2 * nt + (col >> 3);
                red_s[t][w] = s[nt]; red_ss[t][w] = ss[nt];
            }
        }
        __syncthreads();
        float mean[4], rstd[4];
#pragma unroll
        for (int nt = 0; nt < 4; ++nt) {
            int t = 2 * nt + (col >> 3);
            float st  = red_s[t][0] + red_s[t][1] + red_s[t][2] + red_s[t][3];
            float sst = red_ss[t][0] + red_ss[t][1] + red_ss[t][2] + red_ss[t][3];
            mean[nt] = st * (1.f / 1024.f);
            float var = sst * (1.f / 1024.f) - mean[nt] * mean[nt];
            rstd[nt] = rsqrtf(var + 1e-5f);
        }
#pragma unroll
        for (int mtl = 0; mtl < 2; ++mtl) {
            int dq = w * 32 + mtl * 16 + quad * 4;
#pragma unroll
            for (int nt = 0; nt < 4; ++nt) {
                int n = nt * 16 + col; int t = n >> 3, g = n & 7;
                int e = g * D + dq;
                ushort4 o;
#pragma unroll
                for (int r = 0; r < 4; ++r) {
                    float z = (vals[mtl][nt][r] - mean[nt]) * rstd[nt] * bf2f(packgb[e + r])
                              + bf2f(packbb[e + r]);
                    ((u16*)&o)[r] = f2bf(z);
                }
                *(ushort4*)(zout + (tok0 + t) * PK + e) = o;
            }
        }
    }
}

// ---------- z @ Wm + bm via MFMA, 128x128 tiles ----------
template <bool ISBF>
__global__ __launch_bounds__(256)
void gemm_out(const u16* __restrict__ z, const u16* __restrict__ wmt,
              const void* __restrict__ bm, void* __restrict__ out,
              const int* __restrict__ flag) {
    if ((flag[0] != 0) != ISBF) return;
    __shared__ u16 As[128 * 40];   // z tile   [m][k], stride 40
    __shared__ u16 Bs[128 * 40];   // WmT tile [n][k]
    const int tid = threadIdx.x, lane = tid & 63, w = tid >> 6;
    const int quad = lane >> 4, col = lane & 15;
    const int bm0 = (blockIdx.x >> 3) * 128, bn0 = (blockIdx.x & 7) * 128;
    const int wm = w >> 1, wn = w & 1;
    f32x4 acc[4][4] = {};   // [nt][mt]

    for (int k0 = 0; k0 < DM; k0 += 32) {
        __syncthreads();
#pragma unroll
        for (int i = 0; i < 2; ++i) {
            int c = tid * 2 + i; int m = c >> 2, part = c & 3;
            *(short8*)&As[m * 40 + part * 8] =
                *(const short8*)(z + (size_t)(bm0 + m) * DM + k0 + part * 8);
            *(short8*)&Bs[m * 40 + part * 8] =
                *(const short8*)(wmt + (size_t)(bn0 + m) * DM + k0 + part * 8);
        }
        __syncthreads();
        short8 zfr[4], wfr[4];
#pragma unroll
        for (int mt = 0; mt < 4; ++mt)
            zfr[mt] = *(const short8*)&As[(wm * 64 + mt * 16 + col) * 40 + quad * 8];
#pragma unroll
        for (int nt = 0; nt < 4; ++nt)
            wfr[nt] = *(const short8*)&Bs[(wn * 64 + nt * 16 + col) * 40 + quad * 8];
#pragma unroll
        for (int nt = 0; nt < 4; ++nt)
#pragma unroll
            for (int mt = 0; mt < 4; ++mt)
                acc[nt][mt] = __builtin_amdgcn_mfma_f32_16x16x32_bf16(
                    wfr[nt], zfr[mt], acc[nt][mt], 0, 0, 0);
    }
    // epilogue: C rows = n (quad*4+r), cols = m
#pragma unroll
    for (int nt = 0; nt < 4; ++nt) {
        int n = bn0 + wn * 64 + nt * 16 + quad * 4;
        float4 bq = ld4<ISBF>(bm, n);
#pragma unroll
        for (int mt = 0; mt < 4; ++mt) {
            int m = bm0 + wm * 64 + mt * 16 + col;
            float4 o = make_float4(acc[nt][mt][0] + bq.x, acc[nt][mt][1] + bq.y,
                                   acc[nt][mt][2] + bq.z, acc[nt][mt][3] + bq.w);
            st4<ISBF>(out, (size_t)m * DM + n, o);
        }
    }
}

// ---------- scalar fallback (R2-proven), raw weights ----------
template <bool ISBF>
__global__ __launch_bounds__(256)
void slotconv_scalar(const void* __restrict__ x,
                     const void* __restrict__ slot_gate,
                     const void* __restrict__ slot_bias,
                     const void* __restrict__ pre_g,
                     const void* __restrict__ pre_b,
                     const void* __restrict__ w1raw,
                     const void* __restrict__ b1,
                     const void* __restrict__ w2raw,
                     const void* __restrict__ b2,
                     const void* __restrict__ pack_g,
                     const void* __restrict__ pack_b,
                     const void* __restrict__ Wm,
                     const void* __restrict__ bm,
                     void* __restrict__ out,
                     const int* __restrict__ flag) {
    if ((flag[0] != 0) != ISBF) return;
    __shared__ float resid[G * D];
    __shared__ float xnpad[(G + 2) * D];
    __shared__ float midpadf[(G + 2) * H];
    __shared__ float zbuf[4][PK];
    __shared__ float red[8];
    const int tid = threadIdx.x;
    if (tid < D) { xnpad[tid] = 0.f; xnpad[(G + 1) * D + tid] = 0.f; }
    midpadf[tid] = 0.f; midpadf[(G + 1) * H + tid] = 0.f;
    const int e0 = 4 * tid;
    const int d0 = e0 & (D - 1);
    const int g0 = tid >> 5;
    float gate[4], bias[4], pgf[4], pbf[4];
    {
        float4 sg4 = ld4<ISBF>(slot_gate, e0);
        float4 sb4 = ld4<ISBF>(slot_bias, e0);
        float4 pg4 = ld4<ISBF>(pre_g, d0);
        float4 pb4 = ld4<ISBF>(pre_b, d0);
#pragma unroll
        for (int j = 0; j < 4; ++j) {
            gate[j] = 2.f / (1.f + __expf(-f4c(sg4, j)));
            bias[j] = f4c(sb4, j);
            pgf[j] = f4c(pg4, j); pbf[j] = f4c(pb4, j);
        }
    }
    for (int t = 0; t < 4; ++t) {
        __syncthreads();
        const size_t tok = (size_t)blockIdx.x * 4 + t;
        {
            float4 x4 = ld4<ISBF>(x, tok * PK + e0);
            float v[4];
#pragma unroll
            for (int j = 0; j < 4; ++j) v[j] = f4c(x4, j) * gate[j] + bias[j];
            *(float4*)&resid[e0] = make_float4(v[0], v[1], v[2], v[3]);
            float s = v[0]+v[1]+v[2]+v[3], ss = v[0]*v[0]+v[1]*v[1]+v[2]*v[2]+v[3]*v[3];
#pragma unroll
            for (int m = 1; m < 32; m <<= 1) { s += __shfl_xor(s, m); ss += __shfl_xor(ss, m); }
            float mean = s * (1.f/128.f), var = ss * (1.f/128.f) - mean*mean;
            float rstd = rsqrtf(var + 1e-5f);
            float xn[4];
#pragma unroll
            for (int j = 0; j < 4; ++j) xn[j] = (v[j]-mean)*rstd*pgf[j]+pbf[j];
            *(float4*)&xnpad[(g0+1)*D + d0] = make_float4(xn[0],xn[1],xn[2],xn[3]);
        }
        __syncthreads();
        {
            const int h = tid;
            float acc[G];
#pragma unroll
            for (int g = 0; g < G; ++g) acc[g] = 0.f;
            for (int d4 = 0; d4 < D; d4 += 4) {
                float4 xr4[G + 2];
#pragma unroll
                for (int r = 0; r < G + 2; ++r) xr4[r] = *(const float4*)&xnpad[r * D + d4];
#pragma unroll
                for (int j = 0; j < 4; ++j) {
                    size_t o = (size_t)h * (D * 3) + (d4 + j) * 3;
                    float wk0 = ld1<ISBF>(w1raw, o), wk1 = ld1<ISBF>(w1raw, o+1), wk2 = ld1<ISBF>(w1raw, o+2);
#pragma unroll
                    for (int g = 0; g < G; ++g) {
                        acc[g] += f4c(xr4[g+0], j) * wk0;
                        acc[g] += f4c(xr4[g+1], j) * wk1;
                        acc[g] += f4c(xr4[g+2], j) * wk2;
                    }
                }
            }
            float b1h = ld1<ISBF>(b1, tid);
#pragma unroll
            for (int g = 0; g < G; ++g) {
                float m = acc[g] + b1h;
                midpadf[(g+1)*H + h] = 0.5f * m * (1.f + erff(m * 0.70710678118654752f));
            }
        }
        __syncthreads();
        {
            const int dd = tid & (D - 1);
            const int gh = tid >> 7;
            float acc2[4] = {0.f,0.f,0.f,0.f};
            for (int h4 = 0; h4 < H; h4 += 4) {
                float4 mr4[6];
#pragma unroll
                for (int r = 0; r < 6; ++r) mr4[r] = *(const float4*)&midpadf[(gh*4+r)*H + h4];
#pragma unroll
                for (int j = 0; j < 4; ++j) {
                    size_t o = (size_t)dd * (H * 3) + (h4 + j) * 3;
                    float wk0 = ld1<ISBF>(w2raw, o), wk1 = ld1<ISBF>(w2raw, o+1), wk2 = ld1<ISBF>(w2raw, o+2);
#pragma unroll
                    for (int jj = 0; jj < 4; ++jj) {
                        acc2[jj] += f4c(mr4[jj+0], j) * wk0;
                        acc2[jj] += f4c(mr4[jj+1], j) * wk1;
                        acc2[jj] += f4c(mr4[jj+2], j) * wk2;
                    }
                }
            }
            float b2d = ld1<ISBF>(b2, dd);
            float vz[4], s = 0.f, ss = 0.f;
#pragma unroll
            for (int j = 0; j < 4; ++j) {
                int e = (gh*4+j)*D + dd;
                float val = acc2[j] + b2d + resid[e];
                vz[j] = val; s += val; ss += val*val;
            }
#pragma unroll
            for (int m = 1; m < 64; m <<= 1) { s += __shfl_xor(s, m); ss += __shfl_xor(ss, m); }
            const int wid = tid >> 6;
            if ((tid & 63) == 0) { red[wid*2] = s; red[wid*2+1] = ss; }
            __syncthreads();
            float st = red[0]+red[2]+red[4]+red[6], sst = red[1]+red[3]+red[5]+red[7];
            float mean = st * (1.f/1024.f), var = sst * (1.f/1024.f) - mean*mean;
            float rstd = rsqrtf(var + 1e-5f);
#pragma unroll
            for (int j = 0; j < 4; ++j) {
                int e = (gh*4+j)*D + dd;
                zbuf[t][e] = (vz[j]-mean)*rstd*ld1<ISBF>(pack_g, e) + ld1<ISBF>(pack_b, e);
            }
        }
    }
    __syncthreads();
    {
        float accm[4][4];
#pragma unroll
        for (int t = 0; t < 4; ++t)
#pragma unroll
            for (int j = 0; j < 4; ++j) accm[t][j] = 0.f;
        for (int p4 = 0; p4 < PK; p4 += 4) {
            float4 z4[4];
#pragma unroll
            for (int t = 0; t < 4; ++t) z4[t] = *(const float4*)&zbuf[t][p4];
#pragma unroll
            for (int pp = 0; pp < 4; ++pp) {
                float4 w4 = ld4<ISBF>(Wm, (size_t)(p4 + pp) * DM + e0);
#pragma unroll
                for (int t = 0; t < 4; ++t) {
                    float zp = f4c(z4[t], pp);
                    accm[t][0] += zp * w4.x; accm[t][1] += zp * w4.y;
                    accm[t][2] += zp * w4.z; accm[t][3] += zp * w4.w;
                }
            }
        }
        float4 bm4 = ld4<ISBF>(bm, e0);
#pragma unroll
        for (int t = 0; t < 4; ++t) {
            const size_t tok = (size_t)blockIdx.x * 4 + t;
            st4<ISBF>(out, tok * DM + e0,
                      make_float4(accm[t][0]+bm4.x, accm[t][1]+bm4.y,
                                  accm[t][2]+bm4.z, accm[t][3]+bm4.w));
        }
    }
}

extern "C" void kernel_launch(void* const* d_in, const int* in_sizes, int n_in,
                              void* d_out, int out_size, void* d_ws, size_t ws_size,
                              hipStream_t stream) {
    const void* x   = d_in[0];
    const void* sg  = d_in[1];
    const void* sb  = d_in[2];
    const void* pg  = d_in[3];
    const void* pb  = d_in[4];
    const void* w1  = d_in[5];
    const void* b1  = d_in[6];
    const void* w2  = d_in[7];
    const void* b2  = d_in[8];
    const void* pkg = d_in[9];
    const void* pkb = d_in[10];
    const void* Wm  = d_in[11];
    const void* bm  = d_in[12];

    int* flag = (int*)d_ws;
    u16* base = (u16*)((char*)d_ws + 16);
    u16* w1b = base;                       // 98304 el
    u16* w2b = base + 98304;               // 98304 el
    u16* wmt = base + 196608;              // 1048576 el
    u16* zws = base + 196608 + 1048576;    // 16777216 el
    const size_t ws_needed = 16 + (size_t)(98304 + 98304 + 1048576 + 16777216) * sizeof(u16);

    detect_dtype<<<1, 256, 0, stream>>>(x, flag);

    if (ws_size >= ws_needed) {
        prep_mfma<true ><<<(DM * DM + 255) / 256, 256, 0, stream>>>(w1, w2, Wm, w1b, w2b, wmt, flag);
        prep_mfma<false><<<(DM * DM + 255) / 256, 256, 0, stream>>>(w1, w2, Wm, w1b, w2b, wmt, flag);
        conv_fused<true ><<<NTOK / 8, 256, 0, stream>>>(x, sg, sb, pg, pb, b1, b2, pkg, pkb, w1b, w2b, zws, flag);
        conv_fused<false><<<NTOK / 8, 256, 0, stream>>>(x, sg, sb, pg, pb, b1, b2, pkg, pkb, w1b, w2b, zws, flag);
        gemm_out<true ><<<(NTOK / 128) * (DM / 128), 256, 0, stream>>>(zws, wmt, bm, d_out, flag);
        gemm_out<false><<<(NTOK / 128) * (DM / 128), 256, 0, stream>>>(zws, wmt, bm, d_out, flag);
    } else {
        slotconv_scalar<true ><<<NTOK / 4, 256, 0, stream>>>(
            x, sg, sb, pg, pb, w1, b1, w2, b2, pkg, pkb, Wm, bm, d_out, flag);
        slotconv_scalar<false><<<NTOK / 4, 256, 0, stream>>>(
            x, sg, sb, pg, pb, w1, b1, w2, b2, pkg, pkb, Wm, bm, d_out, flag);
    }
}